// Round 4
// baseline (515.230 us; speedup 1.0000x reference)
//
#include <hip/hip_runtime.h>

// Problem constants
#define N_ROWS 32768      // 16*2048 query vectors
#define D_DIM  256        // embedding dim
#define K_CODES 8192      // codebook size

// Output layout (flat float32, reference return order)
#define OUT0_OFF 0                     // z_q_st [16,2048,256]
#define OUT1_OFF 8388608               // z_q    [16,2048,256]
#define OUTI_OFF 16777216              // indices [16,2048] (as float)
#define OUTS_OFF 16809984              // stats [2]

typedef _Float16 half4 __attribute__((ext_vector_type(4)));
typedef _Float16 half8 __attribute__((ext_vector_type(8)));
typedef float    f32x16 __attribute__((ext_vector_type(16)));

// Staged-E image (hi-only fp16): 128 groups of 64 codes. Per group: 2 stages
// (d 0..127 / 128..255), each 64 rows x 256 B. 16-B slot s of row c holds
// dgroup (s - c) & 15 (rotate swizzle -> conflict-free ds_read_b128, linear
// global_load_lds staging). Image = 4 MB, lives in out0 region.
// hn = -0.5*||e||^2 fp32 at +4 MB; candidate lists at +5 MB (4 MB).
#define HN_OFF  0x400000
#define CAND_OFF 0x500000

// Scratch in out1 region: Xh (hi-only fp16 queries, 16 MB).
// ---------------------------------------------------------------------------
// Argmin exactness scheme (hi-only GEMM + margin + exact rescore):
//   q(x,e) = x.e - 0.5||e||^2 ; fp16 approx error |dq| <= 2^-10*||x||*||e||
//   <= 2^-10 * 19 * 1.2 ~ 0.022. Packed-id quantization adds <= 2^-12.
//   MARGIN = 0.05 covers 2*0.022 + quantization. Per query we store top-2
//   per (part x half-lane) bucket = 16 candidates. resolve: if exactly 1
//   stored candidate within MARGIN of stored max -> provably the stored
//   argmax is exact; else rescore all in-margin candidates in fp64 from the
//   original fp32 inputs (tie -> lower index, matching argmin).
#define MARGIN 0.05f

// pack candidate id (6 bits) into the low mantissa bits of a score.
// Ordering by packed float == ordering by score up to 2^-12 perturbation.
#define PK(v, id) __uint_as_float((__float_as_uint(v) & 0xFFFFFFC0u) | (unsigned)(id))

// ---------------------------------------------------------------------------
// Kernel 1: fused input conversion.
// Blocks [0,2048): codebook -> staged hi-fp16 image + folded half-norms.
// Blocks [2048,10240): queries -> hi-fp16 (natural [q][d] layout).
__global__ __launch_bounds__(256) void vq_conv(const float* __restrict__ E,
                                               const float* __restrict__ x,
                                               char* __restrict__ Estg,
                                               float* __restrict__ hn,
                                               char* __restrict__ Xh,
                                               int* __restrict__ usage) {
    if (blockIdx.x < 2048) {
        const int wv = threadIdx.x >> 6;
        const int l = threadIdx.x & 63;
        const int code = blockIdx.x * 4 + wv;
        float4 v = ((const float4*)E)[code * 64 + l];  // d = 4l..4l+3

        const int g = code >> 6, c = code & 63;
        const int st = l >> 5;                  // d>=128 -> stage 1
        const int dg = ((4 * l) & 127) >> 3;    // dgroup within stage (0..15)
        const int slot = (dg + c) & 15;         // rotate swizzle
        const int sub = 8 * (l & 1);            // low/high half of 16-B slot

        half4 hh = {(_Float16)v.x, (_Float16)v.y, (_Float16)v.z, (_Float16)v.w};
        char* p = Estg + (size_t)g * 32768 + st * 16384 + c * 256 + slot * 16 + sub;
        *(half4*)p = hh;

        float s = v.x * v.x + v.y * v.y + v.z * v.z + v.w * v.w;
        #pragma unroll
        for (int off = 32; off >= 1; off >>= 1) s += __shfl_down(s, off);
        if (l == 0) hn[code] = -0.5f * s;

        if (blockIdx.x < K_CODES / 256) usage[blockIdx.x * 256 + threadIdx.x] = 0;
    } else {
        const size_t i4 = ((size_t)(blockIdx.x - 2048) * 256 + threadIdx.x) * 4;
        float4 v = *(const float4*)(x + i4);
        half4 hh = {(_Float16)v.x, (_Float16)v.y, (_Float16)v.z, (_Float16)v.w};
        *(half4*)(Xh + i4 * 2) = hh;
    }
}

// ---------------------------------------------------------------------------
// Kernel 2: hi-only distance GEMM + packed-id fmax scan via MFMA.
// Grid 512 = 128 query-blocks x 4 code-parts (part = blockIdx & 3 so the
// round-robin XCD mapping keeps one 1 MB E-partition per XCD L2).
// 4 waves/block; wave owns 64 queries (2 query tiles, X frags VGPR-resident).
//
// Schedule (T3+T4+T5): 4-buffer LDS ring (4 x 16 KB), depth-3 prefetch via
// global_load_lds; per 128-d stage: counted s_waitcnt vmcnt(8) + raw
// s_barrier (+ compiler-only memory fence), then issue stage s+3, then MFMA
// cluster wrapped in s_setprio(1). Loads are never drained to 0 inside the
// loop (single vmcnt(0) after it). hn lives in LDS so the only vmem ops in
// the loop are the 4 staging loads per stage (clean vmcnt accounting).
// NOTE: no sched_barrier(0) anywhere — R3 showed 64 scheduling walls extend
// live ranges past the VGPR budget and spill the accumulators to scratch
// (WRITE_SIZE 18 MB -> 402 MB). The "" memory-clobber asm orders memory ops
// only and leaves register scheduling free.
#define STAGE_COMPUTE(LDSOFF, KSB)                                             \
    _Pragma("unroll")                                                          \
    for (int ks = 0; ks < 8; ++ks) {                                           \
        const int slot = (2 * ks + hc) & 15;                                   \
        const int sa = rb0 + slot * 16 + (LDSOFF);                             \
        half8 a0 = *(const half8*)(lds + sa);                                  \
        half8 a1 = *(const half8*)(lds + sa + 8192);                           \
        const half8 b0 = xr0[(KSB) + ks];                                      \
        const half8 b1 = xr1[(KSB) + ks];                                      \
        acc00 = __builtin_amdgcn_mfma_f32_32x32x16_f16(a0, b0, acc00, 0, 0, 0);\
        acc01 = __builtin_amdgcn_mfma_f32_32x32x16_f16(a0, b1, acc01, 0, 0, 0);\
        acc10 = __builtin_amdgcn_mfma_f32_32x32x16_f16(a1, b0, acc10, 0, 0, 0);\
        acc11 = __builtin_amdgcn_mfma_f32_32x32x16_f16(a1, b1, acc11, 0, 0, 0);\
    }

// async global->LDS: 16 B per lane; LDS dest = wave-uniform base + lane*16.
// SN wraps mod 64 so in-flight count stays uniform (wrapped issues write
// buffers that are never read again -> harmless; drained after the loop).
#define ISSUE_STAGE(SN, DSTOFF)                                                \
    {                                                                          \
        const char* gs_ = Ebase + (size_t)(((SN) & 63) * 16384);               \
        _Pragma("unroll") for (int i = 0; i < 4; ++i)                          \
            __builtin_amdgcn_global_load_lds(                                  \
                (const __attribute__((address_space(1))) void*)(gs_ + i * 4096 + t16), \
                (__attribute__((address_space(3))) void*)(lds + (DSTOFF) + i * 4096 + t16), \
                16, 0, 0);                                                     \
    }

// counted-wait + raw barrier + compiler memory fence + prefetch issue (T4).
// vmcnt(8): the 4 loads of the stage about to be read land; the 8 newer stay
// in flight. Issue AFTER the barrier: the barrier separates the target
// buffer's last reader (stage s-1 compute, previous phase) from this write.
#define STAGE_SYNC_ISSUE(SN, DSTOFF)                                           \
    asm volatile("s_waitcnt vmcnt(8)" ::: "memory");                           \
    __builtin_amdgcn_s_barrier();                                              \
    asm volatile("" ::: "memory");                                             \
    ISSUE_STAGE(SN, DSTOFF)

// one 64-code group = two 128-d stages + epilogue (chains update).
#define GROUP_BODY(G, SN1, DB1, SRCA, SN2, DB2, SRCB)                          \
    {                                                                          \
        f32x16 acc00 = {}, acc01 = {}, acc10 = {}, acc11 = {};                 \
        STAGE_SYNC_ISSUE(SN1, DB1)                                             \
        __builtin_amdgcn_s_setprio(1);                                         \
        STAGE_COMPUTE(SRCA, 0)                                                 \
        __builtin_amdgcn_s_setprio(0);                                         \
        STAGE_SYNC_ISSUE(SN2, DB2)                                             \
        __builtin_amdgcn_s_setprio(1);                                         \
        STAGE_COMPUTE(SRCB, 8)                                                 \
        __builtin_amdgcn_s_setprio(0);                                         \
        const float4* hq4 = (const float4*)(hn_lds + (G) * 64 + 4 * half);     \
        float4 hn0[4], hn1[4];                                                 \
        _Pragma("unroll") for (int j = 0; j < 4; ++j) {                        \
            hn0[j] = hq4[2 * j];                                               \
            hn1[j] = hq4[2 * j + 8];                                           \
        }                                                                      \
        const int gid2 = (G) * 2;                                              \
        _Pragma("unroll")                                                      \
        for (int r = 0; r < 16; ++r) {                                         \
            const float h0 = hn0[r >> 2][r & 3];                               \
            const float h1 = hn1[r >> 2][r & 3];                               \
            mA[r] = fmaxf(fmaxf(mA[r], PK(acc00[r] + h0, gid2)),               \
                          PK(acc10[r] + h1, gid2 + 1));                        \
            mB[r] = fmaxf(fmaxf(mB[r], PK(acc01[r] + h0, gid2)),               \
                          PK(acc11[r] + h1, gid2 + 1));                        \
        }                                                                      \
    }

#define TOP2_UPD(v, cidx, T0, T1, I0, I1)                                      \
    if ((v) > (T1)) {                                                          \
        const bool g_ = (v) > (T0);                                            \
        (T1) = g_ ? (T0) : (v);                                                \
        (I1) = g_ ? (I0) : (cidx);                                             \
        if (g_) { (T0) = (v); (I0) = (cidx); }                                 \
    }

__global__ __launch_bounds__(256, 2) void vq_mfma(const char* __restrict__ Estg,
                                                  const float* __restrict__ hnp,
                                                  const char* __restrict__ Xh,
                                                  float2* __restrict__ cand) {
    __shared__ __attribute__((aligned(16))) char lds[65536];
    __shared__ __attribute__((aligned(16))) float hn_lds[2048];

    const int tid = threadIdx.x;
    const int w = tid >> 6, lane = tid & 63;
    const int cl = lane & 31, half = lane >> 5;
    const int t16 = tid * 16;
    const int rb0 = cl * 256;       // row base for code tile 0 (tile 1 = +8192)
    const int hc = half + cl;       // swizzle key

    const int part = blockIdx.x & 3;        // code partition (2048 codes)
    const int qb = blockIdx.x >> 2;         // query block (256 queries)
    const char* Ebase = Estg + (size_t)part * 32 * 32768;

    // --- prologue: X fragments resident, 2 query tiles (cols = cl, cl+32) ---
    const int qw = qb * 256 + w * 64;
    const char* xbA = Xh + (size_t)(qw + cl) * 512 + half * 16;
    const char* xbB = Xh + (size_t)(qw + 32 + cl) * 512 + half * 16;
    half8 xr0[16], xr1[16];
    #pragma unroll
    for (int ks = 0; ks < 16; ++ks) {
        xr0[ks] = *(const half8*)(xbA + ks * 32);
        xr1[ks] = *(const half8*)(xbB + ks * 32);
    }

    // stage this part's half-norm slice into LDS (epilogues broadcast-read it;
    // keeps the main loop's vmcnt stream = staging loads only)
    {
        const float4* hsrc = (const float4*)(hnp + part * 2048);
        ((float4*)hn_lds)[tid] = hsrc[tid];
        ((float4*)hn_lds)[tid + 256] = hsrc[tid + 256];
    }
    __syncthreads();   // hn + X landed; vmcnt drained -> clean counting

    // prime: stages 0,1,2 -> buffers 0,1,2 (12 loads in flight)
    ISSUE_STAGE(0, 0)
    ISSUE_STAGE(1, 16384)
    ISSUE_STAGE(2, 32768)

    // 16 independent running-max chains per query tile (packed value|id)
    float mA[16], mB[16];
    #pragma unroll
    for (int r = 0; r < 16; ++r) { mA[r] = -3.4e38f; mB[r] = -3.4e38f; }

    #pragma unroll 1
    for (int gg = 0; gg < 16; ++gg) {
        const int s0 = 4 * gg;
        GROUP_BODY(2 * gg,     s0 + 3, 49152, 0,     s0 + 4, 0,     16384)
        GROUP_BODY(2 * gg + 1, s0 + 5, 16384, 32768, s0 + 6, 32768, 49152)
    }
    asm volatile("s_waitcnt vmcnt(0)" ::: "memory");  // drain wrapped prefetch

    // final: unpack ids, take top-2 per lane-set (runs once; cheap)
    float t0a = -3.4e38f, t1a = -3.4e38f, t0b = -3.4e38f, t1b = -3.4e38f;
    int i0a = 0, i1a = 0, i0b = 0, i1b = 0;
    #pragma unroll
    for (int r = 0; r < 16; ++r) {
        const int rc = (r & 3) + 8 * (r >> 2);
        {
            const unsigned b = __float_as_uint(mA[r]);
            const int id = (int)(b & 63u);
            const int code = (id >> 1) * 64 + (id & 1) * 32 + 4 * half + rc;
            const float v = mA[r];
            TOP2_UPD(v, code, t0a, t1a, i0a, i1a);
        }
        {
            const unsigned b = __float_as_uint(mB[r]);
            const int id = (int)(b & 63u);
            const int code = (id >> 1) * 64 + (id & 1) * 32 + 4 * half + rc;
            const float v = mB[r];
            TOP2_UPD(v, code, t0b, t1b, i0b, i1b);
        }
    }

    // store candidates: [q][part][slot], slot = half*2 + {0,1}; idx global
    const size_t bA = (size_t)(qw + cl) * 16 + part * 4 + half * 2;
    cand[bA]     = make_float2(t0a, __int_as_float(part * 2048 + i0a));
    cand[bA + 1] = make_float2(t1a, __int_as_float(part * 2048 + i1a));
    const size_t bB = (size_t)(qw + 32 + cl) * 16 + part * 4 + half * 2;
    cand[bB]     = make_float2(t0b, __int_as_float(part * 2048 + i0b));
    cand[bB + 1] = make_float2(t1b, __int_as_float(part * 2048 + i1b));
}

// ---------------------------------------------------------------------------
// Kernel 3: resolve exact argmin per query from 16 candidates.
// 4 rows per 256-thread block (one row per wave).
// Fast path (count-in-margin == 1): provably exact. Else fp64 rescore of all
// in-margin candidates from original fp32 inputs (tie -> lower index).
__global__ __launch_bounds__(256) void vq_resolve(const float2* __restrict__ cand,
                                                  const float* __restrict__ x,
                                                  const float* __restrict__ E,
                                                  float* __restrict__ outI,
                                                  int* __restrict__ wsIdx,
                                                  int* __restrict__ usage) {
    const int row = blockIdx.x * 4 + (threadIdx.x >> 6);
    const int lane = threadIdx.x & 63;

    float v = -3.4e38f;
    int ci = 0x7fffffff;
    if (lane < 16) {
        float2 c = cand[(size_t)row * 16 + lane];
        v = c.x;
        ci = __float_as_int(c.y);
    }
    float m = v;
    #pragma unroll
    for (int off = 8; off >= 1; off >>= 1) m = fmaxf(m, __shfl_xor(m, off, 16));
    m = __shfl(m, 0);

    const bool im = (lane < 16) && (v >= m - MARGIN);
    const unsigned long long mk = __ballot(im);
    int besti;
    if (__popcll(mk) == 1) {
        int wmin = im ? ci : 0x7fffffff;
        #pragma unroll
        for (int off = 8; off >= 1; off >>= 1)
            wmin = min(wmin, __shfl_xor(wmin, off, 16));
        besti = __shfl(wmin, 0);
    } else {
        const float4 x4 = *(const float4*)(x + (size_t)row * 256 + lane * 4);
        double bq = -1.0e300;
        besti = 0x7fffffff;
        unsigned long long mm = mk;
        while (mm) {
            const int j = __ffsll(mm) - 1;
            mm &= mm - 1;
            const int cidx = __shfl(ci, j);
            const float4 e4 = *(const float4*)(E + (size_t)cidx * 256 + lane * 4);
            double ps = (double)x4.x * e4.x + (double)x4.y * e4.y +
                        (double)x4.z * e4.z + (double)x4.w * e4.w -
                        0.5 * ((double)e4.x * e4.x + (double)e4.y * e4.y +
                               (double)e4.z * e4.z + (double)e4.w * e4.w);
            #pragma unroll
            for (int off = 32; off >= 1; off >>= 1) ps += __shfl_xor(ps, off);
            if (ps > bq || (ps == bq && cidx < besti)) { bq = ps; besti = cidx; }
        }
    }

    if (lane == 0) {
        outI[row] = (float)besti;
        wsIdx[row] = besti;
        atomicAdd(&usage[besti], 1);
    }
}

// ---------------------------------------------------------------------------
// Kernel 4: gather codebook rows to z_q_st / z_q. 4 rows per block.
__global__ __launch_bounds__(256) void vq_gather(const int* __restrict__ wsIdx,
                                                 const float* __restrict__ E,
                                                 float* __restrict__ out0,
                                                 float* __restrict__ out1) {
    const int row = blockIdx.x * 4 + (threadIdx.x >> 6);
    const int lane = threadIdx.x & 63;
    const int idx = wsIdx[row];
    float4 e4 = ((const float4*)(E + (size_t)idx * D_DIM))[lane];
    ((float4*)(out0 + (size_t)row * D_DIM))[lane] = e4;
    ((float4*)(out1 + (size_t)row * D_DIM))[lane] = e4;
}

// ---------------------------------------------------------------------------
// Kernel 5: perplexity + dead ratio. Single 1024-thread block.
__global__ __launch_bounds__(1024) void vq_stats(const int* __restrict__ usage,
                                                 float* __restrict__ statsOut) {
    __shared__ float redp[1024];
    __shared__ int   redz[1024];
    const int t = threadIdx.x;
    float pl = 0.0f;
    int zc = 0;
    for (int i = t; i < K_CODES; i += 1024) {
        const int u = usage[i];
        if (u == 0) {
            zc++;
        } else {
            const float p = (float)u * (1.0f / (float)N_ROWS);
            pl += p * logf(p);
        }
    }
    redp[t] = pl;
    redz[t] = zc;
    __syncthreads();
    for (int s = 512; s > 0; s >>= 1) {
        if (t < s) { redp[t] += redp[t + s]; redz[t] += redz[t + s]; }
        __syncthreads();
    }
    if (t == 0) {
        statsOut[0] = expf(-redp[0]);
        statsOut[1] = (float)redz[0] / (float)K_CODES;
    }
}

// ---------------------------------------------------------------------------
extern "C" void kernel_launch(void* const* d_in, const int* in_sizes, int n_in,
                              void* d_out, int out_size, void* d_ws, size_t ws_size,
                              hipStream_t stream) {
    const float* z_e = (const float*)d_in[0];   // [16,2048,256] f32
    const float* E   = (const float*)d_in[1];   // [8192,256] f32

    float* out   = (float*)d_out;
    char*  out_b = (char*)d_out;

    // scratch in output regions (overwritten by gather at the end):
    char*   Estg  = out_b;                          // [0, 4 MB) of out0 region
    float*  hn    = (float*)(out_b + HN_OFF);       // 32 KB at +4 MB
    float2* candb = (float2*)(out_b + CAND_OFF);    // 4 MB at +5 MB
    char*   Xh    = out_b + (size_t)OUT1_OFF * 4;   // out1 region: 16 MB

    float* out0 = out + OUT0_OFF;
    float* out1 = out + OUT1_OFF;
    float* outI = out + OUTI_OFF;
    float* outS = out + OUTS_OFF;

    int* usage = (int*)d_ws;                        // 32 KB
    int* wsIdx = (int*)((char*)d_ws + 32768);       // 128 KB

    vq_conv<<<dim3(10240), dim3(256), 0, stream>>>(E, z_e, Estg, hn, Xh, usage);
    vq_mfma<<<dim3(512), dim3(256), 0, stream>>>(Estg, hn, Xh, candb);
    vq_resolve<<<dim3(8192), dim3(256), 0, stream>>>(candb, z_e, E, outI, wsIdx, usage);
    vq_gather<<<dim3(8192), dim3(256), 0, stream>>>(wsIdx, E, out0, out1);
    vq_stats<<<dim3(1), dim3(1024), 0, stream>>>(usage, outS);
}

// Round 5
// 354.697 us; speedup vs baseline: 1.4526x; 1.4526x over previous
//
#include <hip/hip_runtime.h>

// Problem constants
#define N_ROWS 32768      // 16*2048 query vectors
#define D_DIM  256        // embedding dim
#define K_CODES 8192      // codebook size

// Output layout (flat float32, reference return order)
#define OUT0_OFF 0                     // z_q_st [16,2048,256]
#define OUT1_OFF 8388608               // z_q    [16,2048,256]
#define OUTI_OFF 16777216              // indices [16,2048] (as float)
#define OUTS_OFF 16809984              // stats [2]

typedef _Float16 half4 __attribute__((ext_vector_type(4)));
typedef _Float16 half8 __attribute__((ext_vector_type(8)));
typedef float    f32x16 __attribute__((ext_vector_type(16)));

// Staged-E image (hi-only fp16): 128 groups of 64 codes. Per group: 2 stages
// (d 0..127 / 128..255), each 64 rows x 256 B. 16-B slot s of row c holds
// dgroup (s - c) & 15 (rotate swizzle -> conflict-free ds_read_b128, linear
// global_load_lds staging). Image = 4 MB, lives in out0 region.
// hn = -0.5*||e||^2 fp32 at +4 MB; candidate lists at +5 MB (4 MB).
#define HN_OFF  0x400000
#define CAND_OFF 0x500000

// Scratch in out1 region: Xh (hi-only fp16 queries, 16 MB).
// ---------------------------------------------------------------------------
// Argmin exactness scheme (hi-only GEMM + margin + exact rescore):
//   q(x,e) = x.e - 0.5||e||^2 ; fp16 approx error |dq| <= 2^-10*||x||*||e||
//   <= 2^-10 * 19 * 1.2 ~ 0.022. Packed-id quantization adds <= 2^-12.
//   MARGIN = 0.05 covers 2*0.022 + quantization. Per query we store top-2
//   per (part x half-lane) bucket = 16 candidates. resolve: if exactly 1
//   stored candidate within MARGIN of stored max -> provably the stored
//   argmax is exact; else rescore all in-margin candidates in fp64 from the
//   original fp32 inputs (tie -> lower index, matching argmin).
#define MARGIN 0.05f

// pack candidate id (6 bits) into the low mantissa bits of a score.
// Ordering by packed float == ordering by score up to 2^-12 perturbation.
#define PK(v, id) __uint_as_float((__float_as_uint(v) & 0xFFFFFFC0u) | (unsigned)(id))

// ---------------------------------------------------------------------------
// Kernel 1: fused input conversion.
// Blocks [0,2048): codebook -> staged hi-fp16 image + folded half-norms.
// Blocks [2048,10240): queries -> hi-fp16 (natural [q][d] layout).
__global__ __launch_bounds__(256) void vq_conv(const float* __restrict__ E,
                                               const float* __restrict__ x,
                                               char* __restrict__ Estg,
                                               float* __restrict__ hn,
                                               char* __restrict__ Xh,
                                               int* __restrict__ usage) {
    if (blockIdx.x < 2048) {
        const int wv = threadIdx.x >> 6;
        const int l = threadIdx.x & 63;
        const int code = blockIdx.x * 4 + wv;
        float4 v = ((const float4*)E)[code * 64 + l];  // d = 4l..4l+3

        const int g = code >> 6, c = code & 63;
        const int st = l >> 5;                  // d>=128 -> stage 1
        const int dg = ((4 * l) & 127) >> 3;    // dgroup within stage (0..15)
        const int slot = (dg + c) & 15;         // rotate swizzle
        const int sub = 8 * (l & 1);            // low/high half of 16-B slot

        half4 hh = {(_Float16)v.x, (_Float16)v.y, (_Float16)v.z, (_Float16)v.w};
        char* p = Estg + (size_t)g * 32768 + st * 16384 + c * 256 + slot * 16 + sub;
        *(half4*)p = hh;

        float s = v.x * v.x + v.y * v.y + v.z * v.z + v.w * v.w;
        #pragma unroll
        for (int off = 32; off >= 1; off >>= 1) s += __shfl_down(s, off);
        if (l == 0) hn[code] = -0.5f * s;

        if (blockIdx.x < K_CODES / 256) usage[blockIdx.x * 256 + threadIdx.x] = 0;
    } else {
        const size_t i4 = ((size_t)(blockIdx.x - 2048) * 256 + threadIdx.x) * 4;
        float4 v = *(const float4*)(x + i4);
        half4 hh = {(_Float16)v.x, (_Float16)v.y, (_Float16)v.z, (_Float16)v.w};
        *(half4*)(Xh + i4 * 2) = hh;
    }
}

// ---------------------------------------------------------------------------
// Kernel 2: hi-only distance GEMM + packed-id fmax scan via MFMA.
// Grid 512 = 128 query-blocks x 4 code-parts (part = blockIdx & 3 so the
// round-robin XCD mapping keeps one 1 MB E-partition per XCD L2).
// 4 waves/block; wave owns 64 queries (2 query tiles, X frags VGPR-resident).
//
// R2-proven __syncthreads() double-buffer, coarsened: one barrier per 64-code
// GROUP (32 KB staged as one burst of 8 global_load_lds), 2 x 32 KB buffers.
// 32 barriers instead of 64 -> half the vmcnt(0) drain events; each in-flight
// group is covered by 64 MFMAs + epilogue of the current group.
// (R3/R4's inline-asm counted-vmcnt ring caused 400 MB of scratch spill
// traffic twice — reverted to the compiler-managed pattern.)
#define STAGE_COMPUTE(LDSOFF, KSB)                                             \
    _Pragma("unroll")                                                          \
    for (int ks = 0; ks < 8; ++ks) {                                           \
        const int slot = (2 * ks + hc) & 15;                                   \
        const int sa = rb0 + slot * 16 + (LDSOFF);                             \
        half8 a0 = *(const half8*)(lds + sa);                                  \
        half8 a1 = *(const half8*)(lds + sa + 8192);                           \
        const half8 b0 = xr0[(KSB) + ks];                                      \
        const half8 b1 = xr1[(KSB) + ks];                                      \
        acc00 = __builtin_amdgcn_mfma_f32_32x32x16_f16(a0, b0, acc00, 0, 0, 0);\
        acc01 = __builtin_amdgcn_mfma_f32_32x32x16_f16(a0, b1, acc01, 0, 0, 0);\
        acc10 = __builtin_amdgcn_mfma_f32_32x32x16_f16(a1, b0, acc10, 0, 0, 0);\
        acc11 = __builtin_amdgcn_mfma_f32_32x32x16_f16(a1, b1, acc11, 0, 0, 0);\
    }

// async global->LDS: one full 32 KB group (both 128-d stages) per burst.
// 16 B per lane; LDS dest = wave-uniform base + lane*16 (linear).
#define ISSUE_GROUP(SN, DSTOFF)                                                \
    {                                                                          \
        const char* gs_ = Ebase + (size_t)(((SN) & 31) * 32768);               \
        _Pragma("unroll") for (int i = 0; i < 8; ++i)                          \
            __builtin_amdgcn_global_load_lds(                                  \
                (const __attribute__((address_space(1))) void*)(gs_ + i * 4096 + t16), \
                (__attribute__((address_space(3))) void*)(lds + (DSTOFF) + i * 4096 + t16), \
                16, 0, 0);                                                     \
    }

// one 64-code group: barrier (group G landed), prefetch G+1 into the other
// buffer, compute both 128-d stages of G, epilogue (packed-id fmax chains).
#define GROUP_BODY(G, DSTN, SRCB)                                              \
    {                                                                          \
        f32x16 acc00 = {}, acc01 = {}, acc10 = {}, acc11 = {};                 \
        __syncthreads();                                                       \
        ISSUE_GROUP((G) + 1, DSTN)                                             \
        const float* hq = hnp + part * 2048 + (G) * 64 + 4 * half;             \
        float4 hn0[4], hn1[4];                                                 \
        _Pragma("unroll") for (int j = 0; j < 4; ++j) {                        \
            hn0[j] = *(const float4*)(hq + 8 * j);                             \
            hn1[j] = *(const float4*)(hq + 32 + 8 * j);                        \
        }                                                                      \
        STAGE_COMPUTE(SRCB, 0)                                                 \
        STAGE_COMPUTE((SRCB) + 16384, 8)                                       \
        const int gid2 = (G) * 2;                                              \
        _Pragma("unroll")                                                      \
        for (int r = 0; r < 16; ++r) {                                         \
            const float h0 = hn0[r >> 2][r & 3];                               \
            const float h1 = hn1[r >> 2][r & 3];                               \
            mA[r] = fmaxf(fmaxf(mA[r], PK(acc00[r] + h0, gid2)),               \
                          PK(acc10[r] + h1, gid2 + 1));                        \
            mB[r] = fmaxf(fmaxf(mB[r], PK(acc01[r] + h0, gid2)),               \
                          PK(acc11[r] + h1, gid2 + 1));                        \
        }                                                                      \
    }

#define TOP2_UPD(v, cidx, T0, T1, I0, I1)                                      \
    if ((v) > (T1)) {                                                          \
        const bool g_ = (v) > (T0);                                            \
        (T1) = g_ ? (T0) : (v);                                                \
        (I1) = g_ ? (I0) : (cidx);                                             \
        if (g_) { (T0) = (v); (I0) = (cidx); }                                 \
    }

__global__ __launch_bounds__(256, 2) void vq_mfma(const char* __restrict__ Estg,
                                                  const float* __restrict__ hnp,
                                                  const char* __restrict__ Xh,
                                                  float2* __restrict__ cand) {
    __shared__ __attribute__((aligned(16))) char lds[65536];

    const int tid = threadIdx.x;
    const int w = tid >> 6, lane = tid & 63;
    const int cl = lane & 31, half = lane >> 5;
    const int t16 = tid * 16;
    const int rb0 = cl * 256;       // row base for code tile 0 (tile 1 = +8192)
    const int hc = half + cl;       // swizzle key

    const int part = blockIdx.x & 3;        // code partition (2048 codes)
    const int qb = blockIdx.x >> 2;         // query block (256 queries)
    const char* Ebase = Estg + (size_t)part * 32 * 32768;

    // --- prologue: X fragments resident, 2 query tiles (cols = cl, cl+32) ---
    const int qw = qb * 256 + w * 64;
    const char* xbA = Xh + (size_t)(qw + cl) * 512 + half * 16;
    const char* xbB = Xh + (size_t)(qw + 32 + cl) * 512 + half * 16;
    half8 xr0[16], xr1[16];
    #pragma unroll
    for (int ks = 0; ks < 16; ++ks) {
        xr0[ks] = *(const half8*)(xbA + ks * 32);
        xr1[ks] = *(const half8*)(xbB + ks * 32);
    }

    // prime: group 0 -> buf0
    ISSUE_GROUP(0, 0)

    // 16 independent running-max chains per query tile (packed value|id)
    float mA[16], mB[16];
    #pragma unroll
    for (int r = 0; r < 16; ++r) { mA[r] = -3.4e38f; mB[r] = -3.4e38f; }

    #pragma unroll 1
    for (int gg = 0; gg < 16; ++gg) {
        GROUP_BODY(2 * gg,     32768, 0)      // group even: read buf0, load buf1
        GROUP_BODY(2 * gg + 1, 0,     32768)  // group odd:  read buf1, load buf0
    }

    // final: unpack ids, take top-2 per lane-set (runs once; cheap)
    float t0a = -3.4e38f, t1a = -3.4e38f, t0b = -3.4e38f, t1b = -3.4e38f;
    int i0a = 0, i1a = 0, i0b = 0, i1b = 0;
    #pragma unroll
    for (int r = 0; r < 16; ++r) {
        const int rc = (r & 3) + 8 * (r >> 2);
        {
            const unsigned b = __float_as_uint(mA[r]);
            const int id = (int)(b & 63u);
            const int code = (id >> 1) * 64 + (id & 1) * 32 + 4 * half + rc;
            const float v = mA[r];
            TOP2_UPD(v, code, t0a, t1a, i0a, i1a);
        }
        {
            const unsigned b = __float_as_uint(mB[r]);
            const int id = (int)(b & 63u);
            const int code = (id >> 1) * 64 + (id & 1) * 32 + 4 * half + rc;
            const float v = mB[r];
            TOP2_UPD(v, code, t0b, t1b, i0b, i1b);
        }
    }

    // store candidates: [q][part][slot], slot = half*2 + {0,1}; idx global
    const size_t bA = (size_t)(qw + cl) * 16 + part * 4 + half * 2;
    cand[bA]     = make_float2(t0a, __int_as_float(part * 2048 + i0a));
    cand[bA + 1] = make_float2(t1a, __int_as_float(part * 2048 + i1a));
    const size_t bB = (size_t)(qw + 32 + cl) * 16 + part * 4 + half * 2;
    cand[bB]     = make_float2(t0b, __int_as_float(part * 2048 + i0b));
    cand[bB + 1] = make_float2(t1b, __int_as_float(part * 2048 + i1b));
}

// ---------------------------------------------------------------------------
// Kernel 3: resolve exact argmin per query from 16 candidates.
// 4 rows per 256-thread block (one row per wave).
// Fast path (count-in-margin == 1): provably exact. Else fp64 rescore of all
// in-margin candidates from original fp32 inputs (tie -> lower index).
__global__ __launch_bounds__(256) void vq_resolve(const float2* __restrict__ cand,
                                                  const float* __restrict__ x,
                                                  const float* __restrict__ E,
                                                  float* __restrict__ outI,
                                                  int* __restrict__ wsIdx,
                                                  int* __restrict__ usage) {
    const int row = blockIdx.x * 4 + (threadIdx.x >> 6);
    const int lane = threadIdx.x & 63;

    float v = -3.4e38f;
    int ci = 0x7fffffff;
    if (lane < 16) {
        float2 c = cand[(size_t)row * 16 + lane];
        v = c.x;
        ci = __float_as_int(c.y);
    }
    float m = v;
    #pragma unroll
    for (int off = 8; off >= 1; off >>= 1) m = fmaxf(m, __shfl_xor(m, off, 16));
    m = __shfl(m, 0);

    const bool im = (lane < 16) && (v >= m - MARGIN);
    const unsigned long long mk = __ballot(im);
    int besti;
    if (__popcll(mk) == 1) {
        int wmin = im ? ci : 0x7fffffff;
        #pragma unroll
        for (int off = 8; off >= 1; off >>= 1)
            wmin = min(wmin, __shfl_xor(wmin, off, 16));
        besti = __shfl(wmin, 0);
    } else {
        const float4 x4 = *(const float4*)(x + (size_t)row * 256 + lane * 4);
        double bq = -1.0e300;
        besti = 0x7fffffff;
        unsigned long long mm = mk;
        while (mm) {
            const int j = __ffsll(mm) - 1;
            mm &= mm - 1;
            const int cidx = __shfl(ci, j);
            const float4 e4 = *(const float4*)(E + (size_t)cidx * 256 + lane * 4);
            double ps = (double)x4.x * e4.x + (double)x4.y * e4.y +
                        (double)x4.z * e4.z + (double)x4.w * e4.w -
                        0.5 * ((double)e4.x * e4.x + (double)e4.y * e4.y +
                               (double)e4.z * e4.z + (double)e4.w * e4.w);
            #pragma unroll
            for (int off = 32; off >= 1; off >>= 1) ps += __shfl_xor(ps, off);
            if (ps > bq || (ps == bq && cidx < besti)) { bq = ps; besti = cidx; }
        }
    }

    if (lane == 0) {
        outI[row] = (float)besti;
        wsIdx[row] = besti;
        atomicAdd(&usage[besti], 1);
    }
}

// ---------------------------------------------------------------------------
// Kernel 4: gather codebook rows to z_q_st / z_q. 4 rows per block.
__global__ __launch_bounds__(256) void vq_gather(const int* __restrict__ wsIdx,
                                                 const float* __restrict__ E,
                                                 float* __restrict__ out0,
                                                 float* __restrict__ out1) {
    const int row = blockIdx.x * 4 + (threadIdx.x >> 6);
    const int lane = threadIdx.x & 63;
    const int idx = wsIdx[row];
    float4 e4 = ((const float4*)(E + (size_t)idx * D_DIM))[lane];
    ((float4*)(out0 + (size_t)row * D_DIM))[lane] = e4;
    ((float4*)(out1 + (size_t)row * D_DIM))[lane] = e4;
}

// ---------------------------------------------------------------------------
// Kernel 5: perplexity + dead ratio. Single 1024-thread block.
__global__ __launch_bounds__(1024) void vq_stats(const int* __restrict__ usage,
                                                 float* __restrict__ statsOut) {
    __shared__ float redp[1024];
    __shared__ int   redz[1024];
    const int t = threadIdx.x;
    float pl = 0.0f;
    int zc = 0;
    for (int i = t; i < K_CODES; i += 1024) {
        const int u = usage[i];
        if (u == 0) {
            zc++;
        } else {
            const float p = (float)u * (1.0f / (float)N_ROWS);
            pl += p * logf(p);
        }
    }
    redp[t] = pl;
    redz[t] = zc;
    __syncthreads();
    for (int s = 512; s > 0; s >>= 1) {
        if (t < s) { redp[t] += redp[t + s]; redz[t] += redz[t + s]; }
        __syncthreads();
    }
    if (t == 0) {
        statsOut[0] = expf(-redp[0]);
        statsOut[1] = (float)redz[0] / (float)K_CODES;
    }
}

// ---------------------------------------------------------------------------
extern "C" void kernel_launch(void* const* d_in, const int* in_sizes, int n_in,
                              void* d_out, int out_size, void* d_ws, size_t ws_size,
                              hipStream_t stream) {
    const float* z_e = (const float*)d_in[0];   // [16,2048,256] f32
    const float* E   = (const float*)d_in[1];   // [8192,256] f32

    float* out   = (float*)d_out;
    char*  out_b = (char*)d_out;

    // scratch in output regions (overwritten by gather at the end):
    char*   Estg  = out_b;                          // [0, 4 MB) of out0 region
    float*  hn    = (float*)(out_b + HN_OFF);       // 32 KB at +4 MB
    float2* candb = (float2*)(out_b + CAND_OFF);    // 4 MB at +5 MB
    char*   Xh    = out_b + (size_t)OUT1_OFF * 4;   // out1 region: 16 MB

    float* out0 = out + OUT0_OFF;
    float* out1 = out + OUT1_OFF;
    float* outI = out + OUTI_OFF;
    float* outS = out + OUTS_OFF;

    int* usage = (int*)d_ws;                        // 32 KB
    int* wsIdx = (int*)((char*)d_ws + 32768);       // 128 KB

    vq_conv<<<dim3(10240), dim3(256), 0, stream>>>(E, z_e, Estg, hn, Xh, usage);
    vq_mfma<<<dim3(512), dim3(256), 0, stream>>>(Estg, hn, Xh, candb);
    vq_resolve<<<dim3(8192), dim3(256), 0, stream>>>(candb, z_e, E, outI, wsIdx, usage);
    vq_gather<<<dim3(8192), dim3(256), 0, stream>>>(wsIdx, E, out0, out1);
    vq_stats<<<dim3(1), dim3(1024), 0, stream>>>(usage, outS);
}

// Round 6
// 263.005 us; speedup vs baseline: 1.9590x; 1.3486x over previous
//
#include <hip/hip_runtime.h>

// Problem constants
#define N_ROWS 32768      // 16*2048 query vectors
#define D_DIM  256        // embedding dim
#define K_CODES 8192      // codebook size

// Output layout (flat float32, reference return order)
#define OUT0_OFF 0                     // z_q_st [16,2048,256]
#define OUT1_OFF 8388608               // z_q    [16,2048,256]
#define OUTI_OFF 16777216              // indices [16,2048] (as float)
#define OUTS_OFF 16809984              // stats [2]

typedef _Float16 half4 __attribute__((ext_vector_type(4)));
typedef _Float16 half8 __attribute__((ext_vector_type(8)));
typedef float    f32x16 __attribute__((ext_vector_type(16)));

// Staged-E image (hi-only fp16): 128 groups of 64 codes. Per group: 2 stages
// (d 0..127 / 128..255), each 64 rows x 256 B. 16-B slot s of row c holds
// dgroup (s - c) & 15 (rotate swizzle -> conflict-free ds_read_b128, linear
// global_load_lds staging). Image = 4 MB, lives in out0 region.
// hn = -0.5*||e||^2 fp32 at +4 MB; fallback candidate lists at +5 MB.
#define HN_OFF  0x400000
#define CAND_OFF 0x500000

// Scratch in out1 region: Xh (hi-only fp16 queries, 16 MB).
// ---------------------------------------------------------------------------
// Argmin exactness scheme (hi-only GEMM + margin + exact rescore):
//   q(x,e) = x.e - 0.5||e||^2 ; fp16 approx error |dq| <= 2^-10*||x||*||e||
//   <= 2^-10 * 19 * 1.2 ~ 0.022. Packed-id quantization adds <= 2^-12.
//   MARGIN = 0.05 covers 2*0.022 + quantization. Per query we store top-2
//   per (part x half-lane) bucket = 16 candidates. resolve: if exactly 1
//   stored candidate within MARGIN of stored max -> provably the stored
//   argmax is exact; else rescore all in-margin candidates in fp64 from the
//   original fp32 inputs (tie -> lower index, matching argmin).
//
// SCHEDULING NOTE (R3/R4/R5 post-mortems): this kernel's per-wave register
// state (xr 128 VGPR + acc 64 + chains 32) leaves NO headroom. Any schedule
// with a barrier-to-barrier region larger than one 16 KB stage (deep rings,
// merged stages, counted-vmcnt phases) lets the scheduler hoist >16
// ds_read_b128 results and spills to scratch (WRITE_SIZE 18 MB -> 200-400 MB,
// 1.6-2.6x slowdown, observed three times). Keep the R2 shape: one
// __syncthreads() on BOTH sides of each 16 KB compute phase.
#define MARGIN 0.05f

// pack candidate id (6 bits) into the low mantissa bits of a score.
// Ordering by packed float == ordering by score up to 2^-12 perturbation.
#define PK(v, id) __uint_as_float((__float_as_uint(v) & 0xFFFFFFC0u) | (unsigned)(id))

// ---------------------------------------------------------------------------
// Kernel 1: fused input conversion.
// Blocks [0,2048): codebook -> staged hi-fp16 image + folded half-norms.
// Blocks [2048,10240): queries -> hi-fp16 (natural [q][d] layout).
__global__ __launch_bounds__(256) void vq_conv(const float* __restrict__ E,
                                               const float* __restrict__ x,
                                               char* __restrict__ Estg,
                                               float* __restrict__ hn,
                                               char* __restrict__ Xh,
                                               int* __restrict__ usage) {
    if (blockIdx.x < 2048) {
        const int wv = threadIdx.x >> 6;
        const int l = threadIdx.x & 63;
        const int code = blockIdx.x * 4 + wv;
        float4 v = ((const float4*)E)[code * 64 + l];  // d = 4l..4l+3

        const int g = code >> 6, c = code & 63;
        const int st = l >> 5;                  // d>=128 -> stage 1
        const int dg = ((4 * l) & 127) >> 3;    // dgroup within stage (0..15)
        const int slot = (dg + c) & 15;         // rotate swizzle
        const int sub = 8 * (l & 1);            // low/high half of 16-B slot

        half4 hh = {(_Float16)v.x, (_Float16)v.y, (_Float16)v.z, (_Float16)v.w};
        char* p = Estg + (size_t)g * 32768 + st * 16384 + c * 256 + slot * 16 + sub;
        *(half4*)p = hh;

        float s = v.x * v.x + v.y * v.y + v.z * v.z + v.w * v.w;
        #pragma unroll
        for (int off = 32; off >= 1; off >>= 1) s += __shfl_down(s, off);
        if (l == 0) hn[code] = -0.5f * s;

        if (blockIdx.x < K_CODES / 256) usage[blockIdx.x * 256 + threadIdx.x] = 0;
    } else {
        const size_t i4 = ((size_t)(blockIdx.x - 2048) * 256 + threadIdx.x) * 4;
        float4 v = *(const float4*)(x + i4);
        half4 hh = {(_Float16)v.x, (_Float16)v.y, (_Float16)v.z, (_Float16)v.w};
        *(half4*)(Xh + i4 * 2) = hh;
    }
}

// ---------------------------------------------------------------------------
// Kernel 2: hi-only distance GEMM + packed-id fmax scan via MFMA.
// EXACTLY the verified R2 structure (155 us, WRITE 18 MB, MfmaUtil 41%).
// Grid 512 = 128 query-blocks x 4 code-parts (part = blockIdx & 3 so the
// round-robin XCD mapping keeps one 1 MB E-partition per XCD L2).
// 4 waves/block; wave owns 64 queries (2 query tiles, X frags VGPR-resident);
// E streams through a 32 KB LDS double buffer via global_load_lds.
// Per ks: 2 ds_read_b128 feed 4 MFMAs. Epilogue keeps 16 independent
// running-max chains per query (no index selects in the hot loop).
#define STAGE_COMPUTE(LDSOFF, KSB)                                             \
    _Pragma("unroll")                                                          \
    for (int ks = 0; ks < 8; ++ks) {                                           \
        const int slot = (2 * ks + hc) & 15;                                   \
        const int sa = rb0 + slot * 16 + (LDSOFF);                             \
        half8 a0 = *(const half8*)(lds + sa);                                  \
        half8 a1 = *(const half8*)(lds + sa + 8192);                           \
        const half8 b0 = xr0[(KSB) + ks];                                      \
        const half8 b1 = xr1[(KSB) + ks];                                      \
        acc00 = __builtin_amdgcn_mfma_f32_32x32x16_f16(a0, b0, acc00, 0, 0, 0);\
        acc01 = __builtin_amdgcn_mfma_f32_32x32x16_f16(a0, b1, acc01, 0, 0, 0);\
        acc10 = __builtin_amdgcn_mfma_f32_32x32x16_f16(a1, b0, acc10, 0, 0, 0);\
        acc11 = __builtin_amdgcn_mfma_f32_32x32x16_f16(a1, b1, acc11, 0, 0, 0);\
    }

// async global->LDS: 16 B per lane; LDS dest = wave-uniform base + lane*16.
#define ISSUE_STAGE(gsrc, BUFOFF)                                              \
    _Pragma("unroll") for (int i = 0; i < 4; ++i)                              \
        __builtin_amdgcn_global_load_lds(                                      \
            (const __attribute__((address_space(1))) void*)((gsrc) + i * 4096 + t16), \
            (__attribute__((address_space(3))) void*)(lds + (BUFOFF) + i * 4096 + t16), \
            16, 0, 0);

#define TOP2_UPD(v, cidx, T0, T1, I0, I1)                                      \
    if ((v) > (T1)) {                                                          \
        const bool g_ = (v) > (T0);                                            \
        (T1) = g_ ? (T0) : (v);                                                \
        (I1) = g_ ? (I0) : (cidx);                                             \
        if (g_) { (T0) = (v); (I0) = (cidx); }                                 \
    }

__global__ __launch_bounds__(256, 2) void vq_mfma(const char* __restrict__ Estg,
                                                  const float* __restrict__ hnp,
                                                  const char* __restrict__ Xh,
                                                  float2* __restrict__ cand) {
    __shared__ __attribute__((aligned(16))) char lds[32768];

    const int tid = threadIdx.x;
    const int w = tid >> 6, lane = tid & 63;
    const int cl = lane & 31, half = lane >> 5;
    const int t16 = tid * 16;
    const int rb0 = cl * 256;       // row base for code tile 0 (tile 1 = +8192)
    const int hc = half + cl;       // swizzle key

    const int part = blockIdx.x & 3;        // code partition (2048 codes)
    const int qb = blockIdx.x >> 2;         // query block (256 queries)
    const char* Ebase = Estg + (size_t)part * 32 * 32768;

    // --- prologue: X fragments resident, 2 query tiles (cols = cl, cl+32) ---
    const int qw = qb * 256 + w * 64;
    const char* xbA = Xh + (size_t)(qw + cl) * 512 + half * 16;
    const char* xbB = Xh + (size_t)(qw + 32 + cl) * 512 + half * 16;
    half8 xr0[16], xr1[16];
    #pragma unroll
    for (int ks = 0; ks < 16; ++ks) {
        xr0[ks] = *(const half8*)(xbA + ks * 32);
        xr1[ks] = *(const half8*)(xbB + ks * 32);
    }

    // prime: group 0 stage 0 -> buf0
    ISSUE_STAGE(Ebase, 0)

    // 16 independent running-max chains per query tile (packed value|id)
    float mA[16], mB[16];
    #pragma unroll
    for (int r = 0; r < 16; ++r) { mA[r] = -3.4e38f; mB[r] = -3.4e38f; }

    for (int g = 0; g < 32; ++g) {
        const char* egrp = Ebase + (size_t)g * 32768;
        const char* enxt = Ebase + (size_t)((g + 1) & 31) * 32768;

        f32x16 acc00 = {}, acc01 = {}, acc10 = {}, acc11 = {};

        __syncthreads();                 // buf0 (stage 2g) landed; buf1 free
        ISSUE_STAGE(egrp + 16384, 16384) // stage 2g+1 -> buf1
        // per-lane half-norm prefetch for this group's epilogue (L2-hot)
        const float* hq = hnp + part * 2048 + g * 64 + 4 * half;
        float4 hn0[4], hn1[4];
        #pragma unroll
        for (int j = 0; j < 4; ++j) {
            hn0[j] = *(const float4*)(hq + 8 * j);
            hn1[j] = *(const float4*)(hq + 32 + 8 * j);
        }
        STAGE_COMPUTE(0, 0)              // compute d 0..127 from buf0

        __syncthreads();                 // buf1 landed; buf0 free
        ISSUE_STAGE(enxt, 0)             // group g+1 stage 0 -> buf0
        STAGE_COMPUTE(16384, 8)          // compute d 128..255 from buf1

        // epilogue: q = acc + (-0.5||e||^2); pack id, running max per slot.
        // id = g*2 + tile (6 bits); 16 independent chains -> full ILP.
        const int gid2 = g * 2;
        #pragma unroll
        for (int r = 0; r < 16; ++r) {
            const float h0 = hn0[r >> 2][r & 3];
            const float h1 = hn1[r >> 2][r & 3];
            mA[r] = fmaxf(fmaxf(mA[r], PK(acc00[r] + h0, gid2)),
                          PK(acc10[r] + h1, gid2 + 1));
            mB[r] = fmaxf(fmaxf(mB[r], PK(acc01[r] + h0, gid2)),
                          PK(acc11[r] + h1, gid2 + 1));
        }
    }

    // final: unpack ids, take top-2 per lane-set (runs once; cheap)
    float t0a = -3.4e38f, t1a = -3.4e38f, t0b = -3.4e38f, t1b = -3.4e38f;
    int i0a = 0, i1a = 0, i0b = 0, i1b = 0;
    #pragma unroll
    for (int r = 0; r < 16; ++r) {
        const int rc = (r & 3) + 8 * (r >> 2);
        {
            const unsigned b = __float_as_uint(mA[r]);
            const int id = (int)(b & 63u);
            const int code = (id >> 1) * 64 + (id & 1) * 32 + 4 * half + rc;
            const float v = mA[r];
            TOP2_UPD(v, code, t0a, t1a, i0a, i1a);
        }
        {
            const unsigned b = __float_as_uint(mB[r]);
            const int id = (int)(b & 63u);
            const int code = (id >> 1) * 64 + (id & 1) * 32 + 4 * half + rc;
            const float v = mB[r];
            TOP2_UPD(v, code, t0b, t1b, i0b, i1b);
        }
    }

    // store candidates: [q][part][slot], slot = half*2 + {0,1}; idx global
    const size_t bA = (size_t)(qw + cl) * 16 + part * 4 + half * 2;
    cand[bA]     = make_float2(t0a, __int_as_float(part * 2048 + i0a));
    cand[bA + 1] = make_float2(t1a, __int_as_float(part * 2048 + i1a));
    const size_t bB = (size_t)(qw + 32 + cl) * 16 + part * 4 + half * 2;
    cand[bB]     = make_float2(t0b, __int_as_float(part * 2048 + i0b));
    cand[bB + 1] = make_float2(t1b, __int_as_float(part * 2048 + i1b));
}

// ---------------------------------------------------------------------------
// Shared device body: resolve exact argmin for one row from 16 candidates.
// All 64 lanes of the wave return besti.
__device__ __forceinline__ int resolve_row(const float2* __restrict__ cand,
                                           const float* __restrict__ x,
                                           const float* __restrict__ E,
                                           int row, int lane) {
    float v = -3.4e38f;
    int ci = 0x7fffffff;
    if (lane < 16) {
        float2 c = cand[(size_t)row * 16 + lane];
        v = c.x;
        ci = __float_as_int(c.y);
    }
    float m = v;
    #pragma unroll
    for (int off = 8; off >= 1; off >>= 1) m = fmaxf(m, __shfl_xor(m, off, 16));
    m = __shfl(m, 0);

    const bool im = (lane < 16) && (v >= m - MARGIN);
    const unsigned long long mk = __ballot(im);
    int besti;
    if (__popcll(mk) == 1) {
        int wmin = im ? ci : 0x7fffffff;
        #pragma unroll
        for (int off = 8; off >= 1; off >>= 1)
            wmin = min(wmin, __shfl_xor(wmin, off, 16));
        besti = __shfl(wmin, 0);
    } else {
        const float4 x4 = *(const float4*)(x + (size_t)row * 256 + lane * 4);
        double bq = -1.0e300;
        besti = 0x7fffffff;
        unsigned long long mm = mk;
        while (mm) {
            const int j = __ffsll(mm) - 1;
            mm &= mm - 1;
            const int cidx = __shfl(ci, j);
            const float4 e4 = *(const float4*)(E + (size_t)cidx * 256 + lane * 4);
            double ps = (double)x4.x * e4.x + (double)x4.y * e4.y +
                        (double)x4.z * e4.z + (double)x4.w * e4.w -
                        0.5 * ((double)e4.x * e4.x + (double)e4.y * e4.y +
                               (double)e4.z * e4.z + (double)e4.w * e4.w);
            #pragma unroll
            for (int off = 32; off >= 1; off >>= 1) ps += __shfl_xor(ps, off);
            if (ps > bq || (ps == bq && cidx < besti)) { bq = ps; besti = cidx; }
        }
    }
    return besti;
}

// ---------------------------------------------------------------------------
// Kernel 3a (fused path, cand in workspace): resolve + gather in one pass.
// Safe because cand no longer aliases the out0 region being overwritten.
__global__ __launch_bounds__(256) void vq_resolve_gather(
        const float2* __restrict__ cand, const float* __restrict__ x,
        const float* __restrict__ E, float* __restrict__ outI,
        int* __restrict__ usage, float* __restrict__ out0,
        float* __restrict__ out1) {
    const int row = blockIdx.x * 4 + (threadIdx.x >> 6);
    const int lane = threadIdx.x & 63;
    const int besti = resolve_row(cand, x, E, row, lane);

    float4 e4 = ((const float4*)(E + (size_t)besti * D_DIM))[lane];
    ((float4*)(out0 + (size_t)row * D_DIM))[lane] = e4;
    ((float4*)(out1 + (size_t)row * D_DIM))[lane] = e4;
    if (lane == 0) {
        outI[row] = (float)besti;
        atomicAdd(&usage[besti], 1);
    }
}

// ---------------------------------------------------------------------------
// Kernel 3b (fallback, cand in out0 region): resolve only.
__global__ __launch_bounds__(256) void vq_resolve(const float2* __restrict__ cand,
                                                  const float* __restrict__ x,
                                                  const float* __restrict__ E,
                                                  float* __restrict__ outI,
                                                  int* __restrict__ wsIdx,
                                                  int* __restrict__ usage) {
    const int row = blockIdx.x * 4 + (threadIdx.x >> 6);
    const int lane = threadIdx.x & 63;
    const int besti = resolve_row(cand, x, E, row, lane);
    if (lane == 0) {
        outI[row] = (float)besti;
        wsIdx[row] = besti;
        atomicAdd(&usage[besti], 1);
    }
}

// ---------------------------------------------------------------------------
// Kernel 4 (fallback): gather codebook rows to z_q_st / z_q. 4 rows per block.
__global__ __launch_bounds__(256) void vq_gather(const int* __restrict__ wsIdx,
                                                 const float* __restrict__ E,
                                                 float* __restrict__ out0,
                                                 float* __restrict__ out1) {
    const int row = blockIdx.x * 4 + (threadIdx.x >> 6);
    const int lane = threadIdx.x & 63;
    const int idx = wsIdx[row];
    float4 e4 = ((const float4*)(E + (size_t)idx * D_DIM))[lane];
    ((float4*)(out0 + (size_t)row * D_DIM))[lane] = e4;
    ((float4*)(out1 + (size_t)row * D_DIM))[lane] = e4;
}

// ---------------------------------------------------------------------------
// Kernel 5: perplexity + dead ratio. Single 1024-thread block.
__global__ __launch_bounds__(1024) void vq_stats(const int* __restrict__ usage,
                                                 float* __restrict__ statsOut) {
    __shared__ float redp[1024];
    __shared__ int   redz[1024];
    const int t = threadIdx.x;
    float pl = 0.0f;
    int zc = 0;
    for (int i = t; i < K_CODES; i += 1024) {
        const int u = usage[i];
        if (u == 0) {
            zc++;
        } else {
            const float p = (float)u * (1.0f / (float)N_ROWS);
            pl += p * logf(p);
        }
    }
    redp[t] = pl;
    redz[t] = zc;
    __syncthreads();
    for (int s = 512; s > 0; s >>= 1) {
        if (t < s) { redp[t] += redp[t + s]; redz[t] += redz[t + s]; }
        __syncthreads();
    }
    if (t == 0) {
        statsOut[0] = expf(-redp[0]);
        statsOut[1] = (float)redz[0] / (float)K_CODES;
    }
}

// ---------------------------------------------------------------------------
extern "C" void kernel_launch(void* const* d_in, const int* in_sizes, int n_in,
                              void* d_out, int out_size, void* d_ws, size_t ws_size,
                              hipStream_t stream) {
    const float* z_e = (const float*)d_in[0];   // [16,2048,256] f32
    const float* E   = (const float*)d_in[1];   // [8192,256] f32

    float* out   = (float*)d_out;
    char*  out_b = (char*)d_out;

    // scratch in output regions (overwritten by gather at the end):
    char*   Estg  = out_b;                          // [0, 4 MB) of out0 region
    float*  hn    = (float*)(out_b + HN_OFF);       // 32 KB at +4 MB
    char*   Xh    = out_b + (size_t)OUT1_OFF * 4;   // out1 region: 16 MB

    float* out0 = out + OUT0_OFF;
    float* out1 = out + OUT1_OFF;
    float* outI = out + OUTI_OFF;
    float* outS = out + OUTS_OFF;

    int* usage = (int*)d_ws;                        // 32 KB
    int* wsIdx = (int*)((char*)d_ws + 32768);       // 128 KB

    // Candidate buffer (4 MB): prefer workspace (enables fused resolve+gather,
    // since cand then doesn't alias the out0 region). Fallback: out0 scratch.
    const size_t WS_NEED = 32768 + 131072 + 4194304;
    const bool fused = ws_size >= WS_NEED;
    float2* candb = fused ? (float2*)((char*)d_ws + 32768 + 131072)
                          : (float2*)(out_b + CAND_OFF);

    vq_conv<<<dim3(10240), dim3(256), 0, stream>>>(E, z_e, Estg, hn, Xh, usage);
    vq_mfma<<<dim3(512), dim3(256), 0, stream>>>(Estg, hn, Xh, candb);
    if (fused) {
        vq_resolve_gather<<<dim3(8192), dim3(256), 0, stream>>>(
            candb, z_e, E, outI, usage, out0, out1);
    } else {
        vq_resolve<<<dim3(8192), dim3(256), 0, stream>>>(candb, z_e, E, outI, wsIdx, usage);
        vq_gather<<<dim3(8192), dim3(256), 0, stream>>>(wsIdx, E, out0, out1);
    }
    vq_stats<<<dim3(1), dim3(1024), 0, stream>>>(usage, outS);
}

// Round 7
// 260.456 us; speedup vs baseline: 1.9782x; 1.0098x over previous
//
#include <hip/hip_runtime.h>

// Problem constants
#define N_ROWS 32768      // 16*2048 query vectors
#define D_DIM  256        // embedding dim
#define K_CODES 8192      // codebook size

// Output layout (flat float32, reference return order)
#define OUT0_OFF 0                     // z_q_st [16,2048,256]
#define OUT1_OFF 8388608               // z_q    [16,2048,256]
#define OUTI_OFF 16777216              // indices [16,2048] (as float)
#define OUTS_OFF 16809984              // stats [2]

typedef _Float16 half4 __attribute__((ext_vector_type(4)));
typedef _Float16 half8 __attribute__((ext_vector_type(8)));
typedef float    f32x16 __attribute__((ext_vector_type(16)));
typedef float    f32x4  __attribute__((ext_vector_type(4)));

// Staged-E image (hi-only fp16): 128 groups of 64 codes. Per group: 2 stages
// (d 0..127 / 128..255), each 64 rows x 256 B. 16-B slot s of row c holds
// dgroup (s - c) & 15 (rotate swizzle -> conflict-free ds_read_b128, linear
// global_load_lds staging). Image = 4 MB, lives in out0 region.
// hn = -0.5*||e||^2 fp32 at +4 MB; fallback candidate lists at +5 MB.
#define HN_OFF  0x400000
#define CAND_OFF 0x500000

// Scratch in out1 region: Xh (hi-only fp16 queries, 16 MB).
// ---------------------------------------------------------------------------
// Argmin exactness scheme (hi-only GEMM + margin + exact rescore):
//   q(x,e) = x.e - 0.5||e||^2 ; fp16 approx error |dq| <= 2^-10*||x||*||e||
//   <= 2^-10 * 19 * 1.2 ~ 0.022. Packed-id quantization adds <= 2^-12.
//   MARGIN = 0.05 covers 2*0.022 + quantization. Per query we store top-2
//   per (part x half-lane) bucket = 16 candidates. resolve: if exactly 1
//   stored candidate within MARGIN of stored max -> provably the stored
//   argmax is exact; else rescore all in-margin candidates in fp64 from the
//   original fp32 inputs (tie -> lower index, matching argmin).
//
// SCHEDULING NOTE (R3/R4/R5 post-mortems): vq_mfma's per-wave register
// state (xr 128 VGPR + acc 64 + chains 32) leaves NO headroom. Any schedule
// with a barrier-to-barrier region larger than one 16 KB stage (deep rings,
// merged stages, counted-vmcnt phases) lets the scheduler hoist >16
// ds_read_b128 results and spills to scratch (WRITE_SIZE 18 MB -> 200-400 MB,
// 1.6-2.6x slowdown, observed three times). Keep the R2 shape: one
// __syncthreads() on BOTH sides of each 16 KB compute phase. FROZEN.
#define MARGIN 0.05f

// pack candidate id (6 bits) into the low mantissa bits of a score.
// Ordering by packed float == ordering by score up to 2^-12 perturbation.
#define PK(v, id) __uint_as_float((__float_as_uint(v) & 0xFFFFFFC0u) | (unsigned)(id))

// ---------------------------------------------------------------------------
// Kernel 1: fused input conversion.
// Blocks [0,2048): codebook -> staged hi-fp16 image + folded half-norms.
// Blocks [2048,10240): queries -> hi-fp16 (natural [q][d] layout).
__global__ __launch_bounds__(256) void vq_conv(const float* __restrict__ E,
                                               const float* __restrict__ x,
                                               char* __restrict__ Estg,
                                               float* __restrict__ hn,
                                               char* __restrict__ Xh,
                                               int* __restrict__ usage) {
    if (blockIdx.x < 2048) {
        const int wv = threadIdx.x >> 6;
        const int l = threadIdx.x & 63;
        const int code = blockIdx.x * 4 + wv;
        float4 v = ((const float4*)E)[code * 64 + l];  // d = 4l..4l+3

        const int g = code >> 6, c = code & 63;
        const int st = l >> 5;                  // d>=128 -> stage 1
        const int dg = ((4 * l) & 127) >> 3;    // dgroup within stage (0..15)
        const int slot = (dg + c) & 15;         // rotate swizzle
        const int sub = 8 * (l & 1);            // low/high half of 16-B slot

        half4 hh = {(_Float16)v.x, (_Float16)v.y, (_Float16)v.z, (_Float16)v.w};
        char* p = Estg + (size_t)g * 32768 + st * 16384 + c * 256 + slot * 16 + sub;
        *(half4*)p = hh;

        float s = v.x * v.x + v.y * v.y + v.z * v.z + v.w * v.w;
        #pragma unroll
        for (int off = 32; off >= 1; off >>= 1) s += __shfl_down(s, off);
        if (l == 0) hn[code] = -0.5f * s;

        if (blockIdx.x < K_CODES / 256) usage[blockIdx.x * 256 + threadIdx.x] = 0;
    } else {
        const size_t i4 = ((size_t)(blockIdx.x - 2048) * 256 + threadIdx.x) * 4;
        float4 v = *(const float4*)(x + i4);
        half4 hh = {(_Float16)v.x, (_Float16)v.y, (_Float16)v.z, (_Float16)v.w};
        *(half4*)(Xh + i4 * 2) = hh;
    }
}

// ---------------------------------------------------------------------------
// Kernel 2: hi-only distance GEMM + packed-id fmax scan via MFMA.
// EXACTLY the verified R2 structure (155 us, WRITE 18 MB, MfmaUtil 41%).
// Grid 512 = 128 query-blocks x 4 code-parts (part = blockIdx & 3 so the
// round-robin XCD mapping keeps one 1 MB E-partition per XCD L2).
// 4 waves/block; wave owns 64 queries (2 query tiles, X frags VGPR-resident);
// E streams through a 32 KB LDS double buffer via global_load_lds.
// Per ks: 2 ds_read_b128 feed 4 MFMAs. Epilogue keeps 16 independent
// running-max chains per query (no index selects in the hot loop).
#define STAGE_COMPUTE(LDSOFF, KSB)                                             \
    _Pragma("unroll")                                                          \
    for (int ks = 0; ks < 8; ++ks) {                                           \
        const int slot = (2 * ks + hc) & 15;                                   \
        const int sa = rb0 + slot * 16 + (LDSOFF);                             \
        half8 a0 = *(const half8*)(lds + sa);                                  \
        half8 a1 = *(const half8*)(lds + sa + 8192);                           \
        const half8 b0 = xr0[(KSB) + ks];                                      \
        const half8 b1 = xr1[(KSB) + ks];                                      \
        acc00 = __builtin_amdgcn_mfma_f32_32x32x16_f16(a0, b0, acc00, 0, 0, 0);\
        acc01 = __builtin_amdgcn_mfma_f32_32x32x16_f16(a0, b1, acc01, 0, 0, 0);\
        acc10 = __builtin_amdgcn_mfma_f32_32x32x16_f16(a1, b0, acc10, 0, 0, 0);\
        acc11 = __builtin_amdgcn_mfma_f32_32x32x16_f16(a1, b1, acc11, 0, 0, 0);\
    }

// async global->LDS: 16 B per lane; LDS dest = wave-uniform base + lane*16.
#define ISSUE_STAGE(gsrc, BUFOFF)                                              \
    _Pragma("unroll") for (int i = 0; i < 4; ++i)                              \
        __builtin_amdgcn_global_load_lds(                                      \
            (const __attribute__((address_space(1))) void*)((gsrc) + i * 4096 + t16), \
            (__attribute__((address_space(3))) void*)(lds + (BUFOFF) + i * 4096 + t16), \
            16, 0, 0);

#define TOP2_UPD(v, cidx, T0, T1, I0, I1)                                      \
    if ((v) > (T1)) {                                                          \
        const bool g_ = (v) > (T0);                                            \
        (T1) = g_ ? (T0) : (v);                                                \
        (I1) = g_ ? (I0) : (cidx);                                             \
        if (g_) { (T0) = (v); (I0) = (cidx); }                                 \
    }

__global__ __launch_bounds__(256, 2) void vq_mfma(const char* __restrict__ Estg,
                                                  const float* __restrict__ hnp,
                                                  const char* __restrict__ Xh,
                                                  float2* __restrict__ cand) {
    __shared__ __attribute__((aligned(16))) char lds[32768];

    const int tid = threadIdx.x;
    const int w = tid >> 6, lane = tid & 63;
    const int cl = lane & 31, half = lane >> 5;
    const int t16 = tid * 16;
    const int rb0 = cl * 256;       // row base for code tile 0 (tile 1 = +8192)
    const int hc = half + cl;       // swizzle key

    const int part = blockIdx.x & 3;        // code partition (2048 codes)
    const int qb = blockIdx.x >> 2;         // query block (256 queries)
    const char* Ebase = Estg + (size_t)part * 32 * 32768;

    // --- prologue: X fragments resident, 2 query tiles (cols = cl, cl+32) ---
    const int qw = qb * 256 + w * 64;
    const char* xbA = Xh + (size_t)(qw + cl) * 512 + half * 16;
    const char* xbB = Xh + (size_t)(qw + 32 + cl) * 512 + half * 16;
    half8 xr0[16], xr1[16];
    #pragma unroll
    for (int ks = 0; ks < 16; ++ks) {
        xr0[ks] = *(const half8*)(xbA + ks * 32);
        xr1[ks] = *(const half8*)(xbB + ks * 32);
    }

    // prime: group 0 stage 0 -> buf0
    ISSUE_STAGE(Ebase, 0)

    // 16 independent running-max chains per query tile (packed value|id)
    float mA[16], mB[16];
    #pragma unroll
    for (int r = 0; r < 16; ++r) { mA[r] = -3.4e38f; mB[r] = -3.4e38f; }

    for (int g = 0; g < 32; ++g) {
        const char* egrp = Ebase + (size_t)g * 32768;
        const char* enxt = Ebase + (size_t)((g + 1) & 31) * 32768;

        f32x16 acc00 = {}, acc01 = {}, acc10 = {}, acc11 = {};

        __syncthreads();                 // buf0 (stage 2g) landed; buf1 free
        ISSUE_STAGE(egrp + 16384, 16384) // stage 2g+1 -> buf1
        // per-lane half-norm prefetch for this group's epilogue (L2-hot)
        const float* hq = hnp + part * 2048 + g * 64 + 4 * half;
        float4 hn0[4], hn1[4];
        #pragma unroll
        for (int j = 0; j < 4; ++j) {
            hn0[j] = *(const float4*)(hq + 8 * j);
            hn1[j] = *(const float4*)(hq + 32 + 8 * j);
        }
        STAGE_COMPUTE(0, 0)              // compute d 0..127 from buf0

        __syncthreads();                 // buf1 landed; buf0 free
        ISSUE_STAGE(enxt, 0)             // group g+1 stage 0 -> buf0
        STAGE_COMPUTE(16384, 8)          // compute d 128..255 from buf1

        // epilogue: q = acc + (-0.5||e||^2); pack id, running max per slot.
        // id = g*2 + tile (6 bits); 16 independent chains -> full ILP.
        const int gid2 = g * 2;
        #pragma unroll
        for (int r = 0; r < 16; ++r) {
            const float h0 = hn0[r >> 2][r & 3];
            const float h1 = hn1[r >> 2][r & 3];
            mA[r] = fmaxf(fmaxf(mA[r], PK(acc00[r] + h0, gid2)),
                          PK(acc10[r] + h1, gid2 + 1));
            mB[r] = fmaxf(fmaxf(mB[r], PK(acc01[r] + h0, gid2)),
                          PK(acc11[r] + h1, gid2 + 1));
        }
    }

    // final: unpack ids, take top-2 per lane-set (runs once; cheap)
    float t0a = -3.4e38f, t1a = -3.4e38f, t0b = -3.4e38f, t1b = -3.4e38f;
    int i0a = 0, i1a = 0, i0b = 0, i1b = 0;
    #pragma unroll
    for (int r = 0; r < 16; ++r) {
        const int rc = (r & 3) + 8 * (r >> 2);
        {
            const unsigned b = __float_as_uint(mA[r]);
            const int id = (int)(b & 63u);
            const int code = (id >> 1) * 64 + (id & 1) * 32 + 4 * half + rc;
            const float v = mA[r];
            TOP2_UPD(v, code, t0a, t1a, i0a, i1a);
        }
        {
            const unsigned b = __float_as_uint(mB[r]);
            const int id = (int)(b & 63u);
            const int code = (id >> 1) * 64 + (id & 1) * 32 + 4 * half + rc;
            const float v = mB[r];
            TOP2_UPD(v, code, t0b, t1b, i0b, i1b);
        }
    }

    // store candidates: [q][part][slot], slot = half*2 + {0,1}; idx global
    const size_t bA = (size_t)(qw + cl) * 16 + part * 4 + half * 2;
    cand[bA]     = make_float2(t0a, __int_as_float(part * 2048 + i0a));
    cand[bA + 1] = make_float2(t1a, __int_as_float(part * 2048 + i1a));
    const size_t bB = (size_t)(qw + 32 + cl) * 16 + part * 4 + half * 2;
    cand[bB]     = make_float2(t0b, __int_as_float(part * 2048 + i0b));
    cand[bB + 1] = make_float2(t1b, __int_as_float(part * 2048 + i1b));
}

// ---------------------------------------------------------------------------
// fp64 exact rescore of one row over a candidate mask (full wave).
// cidx values are fetched from lane (srcBase + bit) of `ci`.
__device__ __forceinline__ int rescore_row(const float* __restrict__ x,
                                           const float* __restrict__ E,
                                           int row, int lane, int ci,
                                           unsigned mk, int srcBase) {
    const float4 x4 = *(const float4*)(x + (size_t)row * 256 + lane * 4);
    double bq = -1.0e300;
    int besti = 0x7fffffff;
    while (mk) {
        const int b = __ffs(mk) - 1;
        mk &= mk - 1;
        const int cidx = __shfl(ci, srcBase + b);
        const float4 e4 = *(const float4*)(E + (size_t)cidx * 256 + lane * 4);
        double ps = (double)x4.x * e4.x + (double)x4.y * e4.y +
                    (double)x4.z * e4.z + (double)x4.w * e4.w -
                    0.5 * ((double)e4.x * e4.x + (double)e4.y * e4.y +
                           (double)e4.z * e4.z + (double)e4.w * e4.w);
        #pragma unroll
        for (int off = 32; off >= 1; off >>= 1) ps += __shfl_xor(ps, off);
        if (ps > bq || (ps == bq && cidx < besti)) { bq = ps; besti = cidx; }
    }
    return besti;
}

// ---------------------------------------------------------------------------
// Kernel 3a (fused path, cand in workspace): resolve + gather, 4 rows/WAVE.
// Block = 4 waves = 16 contiguous rows; grid 2048. Candidate phase uses all
// 64 lanes (4 rows x 16 candidates); slow-path rescore loops only flagged
// rows with the full wave; output writes are 4 KB-contiguous nontemporal.
__global__ __launch_bounds__(256) void vq_resolve_gather(
        const float2* __restrict__ cand, const float* __restrict__ x,
        const float* __restrict__ E, float* __restrict__ outI,
        int* __restrict__ usage, float* __restrict__ out0,
        float* __restrict__ out1) {
    const int lane = threadIdx.x & 63;
    const int sub = lane >> 4;                  // row within the wave's quad
    const int s = lane & 15;                    // candidate slot
    const int row4 = blockIdx.x * 16 + (threadIdx.x >> 6) * 4;  // wave's rows

    // load 64 candidates = 4 rows x 16 (fully coalesced float2)
    float2 c = cand[(size_t)(row4 + sub) * 16 + s];
    const float v = c.x;
    const int ci = __float_as_int(c.y);

    // per-16-group max
    float m = v;
    #pragma unroll
    for (int off = 8; off >= 1; off >>= 1) m = fmaxf(m, __shfl_xor(m, off, 16));

    const bool im = v >= m - MARGIN;
    const unsigned long long bal = __ballot(im);
    const unsigned mkg = (unsigned)((bal >> (16 * sub)) & 0xFFFFULL);
    const int cntg = __popc(mkg);

    // fast path: group min-index over in-margin lanes (valid when cntg==1)
    int wmin = im ? ci : 0x7fffffff;
    #pragma unroll
    for (int off = 8; off >= 1; off >>= 1)
        wmin = min(wmin, __shfl_xor(wmin, off, 16));
    int besti_g = wmin;   // group-uniform

    // slow path: full-wave fp64 rescore for rows with >1 in-margin candidate
    #pragma unroll
    for (int j = 0; j < 4; ++j) {
        const int cnt_j = __shfl(cntg, 16 * j);
        if (cnt_j > 1) {
            const unsigned mk_j = (unsigned)((bal >> (16 * j)) & 0xFFFFULL);
            const int bi = rescore_row(x, E, row4 + j, lane, ci, mk_j, 16 * j);
            if (sub == j) besti_g = bi;
        }
    }

    // gather + write 4 contiguous rows (1 KB per row, nontemporal stream)
    #pragma unroll
    for (int j = 0; j < 4; ++j) {
        const int bi = __shfl(besti_g, 16 * j);
        f32x4 e4 = ((const f32x4*)(E + (size_t)bi * D_DIM))[lane];
        __builtin_nontemporal_store(e4, (f32x4*)(out0 + (size_t)(row4 + j) * D_DIM) + lane);
        __builtin_nontemporal_store(e4, (f32x4*)(out1 + (size_t)(row4 + j) * D_DIM) + lane);
    }
    if (s == 0) {
        outI[row4 + sub] = (float)besti_g;
        atomicAdd(&usage[besti_g], 1);
    }
}

// ---------------------------------------------------------------------------
// Kernel 3b (fallback, cand in out0 region): resolve only, 1 row per wave.
__global__ __launch_bounds__(256) void vq_resolve(const float2* __restrict__ cand,
                                                  const float* __restrict__ x,
                                                  const float* __restrict__ E,
                                                  float* __restrict__ outI,
                                                  int* __restrict__ wsIdx,
                                                  int* __restrict__ usage) {
    const int row = blockIdx.x * 4 + (threadIdx.x >> 6);
    const int lane = threadIdx.x & 63;

    float v = -3.4e38f;
    int ci = 0x7fffffff;
    if (lane < 16) {
        float2 c = cand[(size_t)row * 16 + lane];
        v = c.x;
        ci = __float_as_int(c.y);
    }
    float m = v;
    #pragma unroll
    for (int off = 8; off >= 1; off >>= 1) m = fmaxf(m, __shfl_xor(m, off, 16));
    m = __shfl(m, 0);

    const bool im = (lane < 16) && (v >= m - MARGIN);
    const unsigned long long mk = __ballot(im);
    int besti;
    if (__popcll(mk) == 1) {
        int wmin = im ? ci : 0x7fffffff;
        #pragma unroll
        for (int off = 8; off >= 1; off >>= 1)
            wmin = min(wmin, __shfl_xor(wmin, off, 16));
        besti = __shfl(wmin, 0);
    } else {
        besti = rescore_row(x, E, row, lane, ci, (unsigned)(mk & 0xFFFFULL), 0);
    }

    if (lane == 0) {
        outI[row] = (float)besti;
        wsIdx[row] = besti;
        atomicAdd(&usage[besti], 1);
    }
}

// ---------------------------------------------------------------------------
// Kernel 4 (fallback): gather codebook rows to z_q_st / z_q. 4 rows per block.
__global__ __launch_bounds__(256) void vq_gather(const int* __restrict__ wsIdx,
                                                 const float* __restrict__ E,
                                                 float* __restrict__ out0,
                                                 float* __restrict__ out1) {
    const int row = blockIdx.x * 4 + (threadIdx.x >> 6);
    const int lane = threadIdx.x & 63;
    const int idx = wsIdx[row];
    float4 e4 = ((const float4*)(E + (size_t)idx * D_DIM))[lane];
    ((float4*)(out0 + (size_t)row * D_DIM))[lane] = e4;
    ((float4*)(out1 + (size_t)row * D_DIM))[lane] = e4;
}

// ---------------------------------------------------------------------------
// Kernel 5: perplexity + dead ratio. Single 1024-thread block.
__global__ __launch_bounds__(1024) void vq_stats(const int* __restrict__ usage,
                                                 float* __restrict__ statsOut) {
    __shared__ float redp[1024];
    __shared__ int   redz[1024];
    const int t = threadIdx.x;
    float pl = 0.0f;
    int zc = 0;
    for (int i = t; i < K_CODES; i += 1024) {
        const int u = usage[i];
        if (u == 0) {
            zc++;
        } else {
            const float p = (float)u * (1.0f / (float)N_ROWS);
            pl += p * logf(p);
        }
    }
    redp[t] = pl;
    redz[t] = zc;
    __syncthreads();
    for (int s = 512; s > 0; s >>= 1) {
        if (t < s) { redp[t] += redp[t + s]; redz[t] += redz[t + s]; }
        __syncthreads();
    }
    if (t == 0) {
        statsOut[0] = expf(-redp[0]);
        statsOut[1] = (float)redz[0] / (float)K_CODES;
    }
}

// ---------------------------------------------------------------------------
extern "C" void kernel_launch(void* const* d_in, const int* in_sizes, int n_in,
                              void* d_out, int out_size, void* d_ws, size_t ws_size,
                              hipStream_t stream) {
    const float* z_e = (const float*)d_in[0];   // [16,2048,256] f32
    const float* E   = (const float*)d_in[1];   // [8192,256] f32

    float* out   = (float*)d_out;
    char*  out_b = (char*)d_out;

    // scratch in output regions (overwritten by gather at the end):
    char*   Estg  = out_b;                          // [0, 4 MB) of out0 region
    float*  hn    = (float*)(out_b + HN_OFF);       // 32 KB at +4 MB
    char*   Xh    = out_b + (size_t)OUT1_OFF * 4;   // out1 region: 16 MB

    float* out0 = out + OUT0_OFF;
    float* out1 = out + OUT1_OFF;
    float* outI = out + OUTI_OFF;
    float* outS = out + OUTS_OFF;

    int* usage = (int*)d_ws;                        // 32 KB
    int* wsIdx = (int*)((char*)d_ws + 32768);       // 128 KB

    // Candidate buffer (4 MB): prefer workspace (enables fused resolve+gather,
    // since cand then doesn't alias the out0 region). Fallback: out0 scratch.
    const size_t WS_NEED = 32768 + 131072 + 4194304;
    const bool fused = ws_size >= WS_NEED;
    float2* candb = fused ? (float2*)((char*)d_ws + 32768 + 131072)
                          : (float2*)(out_b + CAND_OFF);

    vq_conv<<<dim3(10240), dim3(256), 0, stream>>>(E, z_e, Estg, hn, Xh, usage);
    vq_mfma<<<dim3(512), dim3(256), 0, stream>>>(Estg, hn, Xh, candb);
    if (fused) {
        vq_resolve_gather<<<dim3(2048), dim3(256), 0, stream>>>(
            candb, z_e, E, outI, usage, out0, out1);
    } else {
        vq_resolve<<<dim3(8192), dim3(256), 0, stream>>>(candb, z_e, E, outI, wsIdx, usage);
        vq_gather<<<dim3(8192), dim3(256), 0, stream>>>(wsIdx, E, out0, out1);
    }
    vq_stats<<<dim3(1), dim3(1024), 0, stream>>>(usage, outS);
}